// Round 1
// baseline (398.221 us; speedup 1.0000x reference)
//
#include <hip/hip_runtime.h>

// GraphFeaturesStackPad on MI355X.
// Stage 1: bf16 MFMA fused up/gate projection + sigmoid-gate + segment-sum
//          (atomicAdd into d_out used as graph_sums accumulator, fp32).
// Stage 2: fp32 in-place GEMM graph_sums @ W_func + b_func  (each block stages
//          its own 32 rows into LDS before overwriting them -> in-place safe).
// d_ws usage: ntiles ints (~31 KB) for per-tile first-graph index.

typedef __bf16 bf16_t;
typedef bf16_t bf16x8 __attribute__((ext_vector_type(8)));
typedef float  f32x4  __attribute__((ext_vector_type(4)));

__device__ __forceinline__ unsigned short f2bf(float f) {
  unsigned int u = __float_as_uint(f);
  u += 0x7fffu + ((u >> 16) & 1u);   // RNE
  return (unsigned short)(u >> 16);
}

// LDS-only barrier: drains LDS ops but leaves global loads (vmcnt) in flight,
// so the software-pipelined next-tile loads overlap the compute phases.
__device__ __forceinline__ void bar_lds() {
  asm volatile("s_waitcnt lgkmcnt(0)\n\ts_barrier" ::: "memory");
}

__global__ void tile_seg_kernel(const int* __restrict__ starts,
                                int* __restrict__ tile_seg,
                                int ntiles, int G) {
  int i = blockIdx.x * blockDim.x + threadIdx.x;
  if (i >= ntiles) return;
  int n0 = i * 64;
  int lo = 0, hi = G - 1;            // largest g with starts[g] <= n0
  while (lo < hi) {
    int mid = (lo + hi + 1) >> 1;
    if (starts[mid] <= n0) lo = mid; else hi = mid - 1;
  }
  tile_seg[i] = lo;
}

__global__ __launch_bounds__(256, 2)
void stage1_kernel(const float* __restrict__ X,
                   const float* __restrict__ Wu, const float* __restrict__ bu,
                   const float* __restrict__ Wg, const float* __restrict__ bg,
                   const int* __restrict__ starts,
                   const int* __restrict__ tile_seg,
                   float* __restrict__ gsum, int V, int ntiles)
{
  __shared__ unsigned short Xs[64 * 136]; // bf16 tile, stride 136 (2-way banks = free)
  __shared__ float          Gs[64 * 132]; // gated fp32 tile, stride 132 (conflict-free)

  const int tid  = threadIdx.x;
  const int lane = tid & 63;
  const int wave = tid >> 6;          // 4 waves; wave owns f-strip [wave*32, wave*32+32)
  const int quad = lane >> 4;
  const int l15  = lane & 15;

  // Persistent B fragments (W_up / W_gate) in registers, loaded once per block.
  // B-frag layout: lane holds B[k = s*32 + quad*8 + j][n = lane&15].
  bf16x8 Bu[2][4], Bg[2][4];
  float bup[2], bgt[2];
#pragma unroll
  for (int t = 0; t < 2; ++t) {
    const int f = wave * 32 + t * 16 + l15;
    bup[t] = bu[f];
    bgt[t] = bg[f];
#pragma unroll
    for (int s = 0; s < 4; ++s) {
      const int k0 = s * 32 + quad * 8;
      union { unsigned short us[8]; bf16x8 v; } a, b;
#pragma unroll
      for (int j = 0; j < 8; ++j) {
        a.us[j] = f2bf(Wu[(k0 + j) * 128 + f]);
        b.us[j] = f2bf(Wg[(k0 + j) * 128 + f]);
      }
      Bu[t][s] = a.v;
      Bg[t][s] = b.v;
    }
  }

  f32x4 ld[8];
  int tile = blockIdx.x;

  // preload first tile (64 nodes x 128 k as float4: flat = tid + i*256)
  {
    const int n0 = tile * 64;
#pragma unroll
    for (int i = 0; i < 8; ++i) {
      const int flat = tid + i * 256;
      const int n = n0 + (flat >> 5);
      const int k = (flat & 31) << 2;
      if (n < V) ld[i] = *(const f32x4*)(X + (size_t)n * 128 + k);
      else       ld[i] = f32x4{0.f, 0.f, 0.f, 0.f};
    }
  }

  for (; tile < ntiles; tile += gridDim.x) {
    const int n0    = tile * 64;
    const int n_end = min(n0 + 64, V);

    // staged regs -> LDS as packed bf16 (8B ds_write, 2-way banks = free)
#pragma unroll
    for (int i = 0; i < 8; ++i) {
      const int flat = tid + i * 256;
      const int n = flat >> 5;
      const int k = (flat & 31) << 2;
      const unsigned int p0 =
          (unsigned int)f2bf(ld[i][0]) | ((unsigned int)f2bf(ld[i][1]) << 16);
      const unsigned int p1 =
          (unsigned int)f2bf(ld[i][2]) | ((unsigned int)f2bf(ld[i][3]) << 16);
      *(uint2*)&Xs[n * 136 + k] = make_uint2(p0, p1);
    }

    // issue next tile's global loads NOW; they stay in flight through the
    // lgkm-only barriers and the MFMA/reduce phases (consumed next iteration)
    const int next = tile + gridDim.x;
    if (next < ntiles) {
      const int m0 = next * 64;
#pragma unroll
      for (int i = 0; i < 8; ++i) {
        const int flat = tid + i * 256;
        const int n = m0 + (flat >> 5);
        const int k = (flat & 31) << 2;
        if (n < V) ld[i] = *(const f32x4*)(X + (size_t)n * 128 + k);
        else       ld[i] = f32x4{0.f, 0.f, 0.f, 0.f};
      }
    }

    bar_lds();

    // ---- MFMA phase: 4 node sub-tiles of 16; per wave 2 f-tiles x 2 mats ----
#pragma unroll
    for (int sub = 0; sub < 4; ++sub) {
      bf16x8 A[4];
      const int nl = sub * 16 + l15;   // A-frag: A[m=lane&15][k=quad*8+j]
#pragma unroll
      for (int s = 0; s < 4; ++s)
        A[s] = *(const bf16x8*)&Xs[nl * 136 + s * 32 + quad * 8];
#pragma unroll
      for (int t = 0; t < 2; ++t) {
        f32x4 au = {0.f, 0.f, 0.f, 0.f};
        f32x4 ag = {0.f, 0.f, 0.f, 0.f};
#pragma unroll
        for (int s = 0; s < 4; ++s) {
          au = __builtin_amdgcn_mfma_f32_16x16x32_bf16(A[s], Bu[t][s], au, 0, 0, 0);
          ag = __builtin_amdgcn_mfma_f32_16x16x32_bf16(A[s], Bg[t][s], ag, 0, 0, 0);
        }
        // D layout: col=lane&15 (feature), row=quad*4+r (node)
        const int f = wave * 32 + t * 16 + l15;
#pragma unroll
        for (int r = 0; r < 4; ++r) {
          const float up = au[r] + bup[t];
          const float gt = ag[r] + bgt[t];
          const float gv = up / (1.f + __expf(-gt));
          Gs[(sub * 16 + quad * 4 + r) * 132 + f] = gv;
        }
      }
    }

    bar_lds();

    // ---- segment reduction: per-graph row sums -> one atomic per (g,f) ----
    {
      int g = tile_seg[tile];
      const int fcol = tid & 127;
      const int half = tid >> 7;       // halves take alternating graphs
      int sg = starts[g];
      while (sg < n_end) {
        const int snext = starts[g + 1];
        if ((g & 1) == half) {
          const int r0 = max(sg, n0) - n0;
          const int r1 = min(snext - 1, n_end) - n0;  // excludes graph's last node
          if (r1 > r0) {
            float acc = 0.f;
            for (int r = r0; r < r1; ++r) acc += Gs[r * 132 + fcol];
            atomicAdd(&gsum[(size_t)g * 128 + fcol], acc);
          }
        }
        ++g;
        sg = snext;
      }
    }

    bar_lds();
  }
}

__global__ __launch_bounds__(256)
void stage2_kernel(const float* __restrict__ Wf, const float* __restrict__ bfv,
                   float* __restrict__ out, int G)
{
  __shared__ float Gsm[32 * 132];
  const int g0  = blockIdx.x * 32;
  const int tid = threadIdx.x;

  // stage this block's 32 graph_sums rows (then safe to overwrite in-place)
  for (int i = tid; i < 32 * 32; i += 256) {
    const int r = i >> 5;
    const int c = (i & 31) << 2;
    const int g = g0 + r;
    f32x4 v = {0.f, 0.f, 0.f, 0.f};
    if (g < G) v = *(const f32x4*)(out + (size_t)g * 128 + c);
    *(f32x4*)&Gsm[r * 132 + c] = v;
  }
  __syncthreads();

  const int fq  = tid & 31;
  const int f0  = fq << 2;            // 4 consecutive features
  const int grp = tid >> 5;           // 8 groups x 4 graphs
  float acc[4][4];
#pragma unroll
  for (int i = 0; i < 4; ++i)
#pragma unroll
    for (int j = 0; j < 4; ++j) acc[i][j] = 0.f;

#pragma unroll 4
  for (int k = 0; k < 128; ++k) {
    const f32x4 w = *(const f32x4*)(Wf + (size_t)k * 128 + f0);
#pragma unroll
    for (int i = 0; i < 4; ++i) {
      const float gv = Gsm[(grp * 4 + i) * 132 + k];
      acc[i][0] += gv * w[0];
      acc[i][1] += gv * w[1];
      acc[i][2] += gv * w[2];
      acc[i][3] += gv * w[3];
    }
  }

  const f32x4 bb = *(const f32x4*)(bfv + f0);
#pragma unroll
  for (int i = 0; i < 4; ++i) {
    const int g = g0 + grp * 4 + i;
    if (g < G) {
      f32x4 o = {acc[i][0] + bb[0], acc[i][1] + bb[1],
                 acc[i][2] + bb[2], acc[i][3] + bb[3]};
      *(f32x4*)(out + (size_t)g * 128 + f0) = o;
    }
  }
}

extern "C" void kernel_launch(void* const* d_in, const int* in_sizes, int n_in,
                              void* d_out, int out_size, void* d_ws, size_t ws_size,
                              hipStream_t stream)
{
  const float* X      = (const float*)d_in[0];
  const float* Wu     = (const float*)d_in[1];
  const float* bu     = (const float*)d_in[2];
  const float* Wg     = (const float*)d_in[3];
  const float* bg     = (const float*)d_in[4];
  const float* Wf     = (const float*)d_in[5];
  const float* bf_    = (const float*)d_in[6];
  const int*   starts = (const int*)d_in[7];

  const int G = in_sizes[7] - 1;
  const int V = in_sizes[0] / 128;
  const int ntiles = (V + 63) / 64;

  int*   tile_seg = (int*)d_ws;          // ntiles ints (~31 KB)
  float* gsum     = (float*)d_out;       // graph_sums accumulates in d_out

  hipMemsetAsync(d_out, 0, (size_t)G * 128 * sizeof(float), stream);
  tile_seg_kernel<<<(ntiles + 255) / 256, 256, 0, stream>>>(starts, tile_seg, ntiles, G);
  stage1_kernel<<<512, 256, 0, stream>>>(X, Wu, bu, Wg, bg, starts, tile_seg,
                                         gsum, V, ntiles);
  stage2_kernel<<<(G + 31) / 32, 256, 0, stream>>>(Wf, bf_, gsum, G);
}

// Round 2
// 395.260 us; speedup vs baseline: 1.0075x; 1.0075x over previous
//
#include <hip/hip_runtime.h>

// GraphFeaturesStackPad on MI355X.
// Stage 1: bf16 MFMA fused up/gate projection + sigmoid-gate + segment-sum
//          (atomicAdd into d_out used as graph_sums accumulator, fp32).
// Stage 2: fp32 in-place GEMM graph_sums @ W_func + b_func  (each block stages
//          its own 32 rows into LDS before overwriting them -> in-place safe).
// d_ws usage: ntiles ints (~31 KB) for per-tile first-graph index.
//
// R2 changes vs R1 (theory: stage1 latency-exposed, not BW-bound):
//  - per-tile starts window staged to LDS (kills serial L2 chase in reduce)
//  - sigmoid uses v_rcp_f32 instead of full-precision fp32 divide
//  - Xs stride 136->144 shorts (A-frag ds_read_b128 8-way -> 4-way banks)
//  - reduce inner loop unrolled x4 (independent partials hide LDS latency)
//  - 3 barriers/tile -> 2 (end-of-loop barrier redundant: next iter's bar1
//    already separates Gs reads from next MFMA-phase Gs writes)

typedef __bf16 bf16_t;
typedef bf16_t bf16x8 __attribute__((ext_vector_type(8)));
typedef float  f32x4  __attribute__((ext_vector_type(4)));

#define XS_STRIDE 144   // shorts; 288 B row = 72 dwords -> 4-way banks on b128
#define GS_STRIDE 132   // floats; 2-way (free) on both write and read sides

__device__ __forceinline__ unsigned short f2bf(float f) {
  unsigned int u = __float_as_uint(f);
  u += 0x7fffu + ((u >> 16) & 1u);   // RNE
  return (unsigned short)(u >> 16);
}

// LDS-only barrier: drains LDS ops but leaves global loads (vmcnt) in flight,
// so the software-pipelined next-tile loads overlap the compute phases.
__device__ __forceinline__ void bar_lds() {
  asm volatile("s_waitcnt lgkmcnt(0)\n\ts_barrier" ::: "memory");
}

__global__ void tile_seg_kernel(const int* __restrict__ starts,
                                int* __restrict__ tile_seg,
                                int ntiles, int G) {
  int i = blockIdx.x * blockDim.x + threadIdx.x;
  if (i >= ntiles) return;
  int n0 = i * 64;
  int lo = 0, hi = G - 1;            // largest g with starts[g] <= n0
  while (lo < hi) {
    int mid = (lo + hi + 1) >> 1;
    if (starts[mid] <= n0) lo = mid; else hi = mid - 1;
  }
  tile_seg[i] = lo;
}

__global__ __launch_bounds__(256, 2)
void stage1_kernel(const float* __restrict__ X,
                   const float* __restrict__ Wu, const float* __restrict__ bu,
                   const float* __restrict__ Wg, const float* __restrict__ bg,
                   const int* __restrict__ starts,
                   const int* __restrict__ tile_seg,
                   float* __restrict__ gsum, int V, int G, int ntiles)
{
  __shared__ unsigned short Xs[64 * XS_STRIDE]; // bf16 tile (18.4 KB)
  __shared__ float          Gs[64 * GS_STRIDE]; // gated fp32 tile (33.8 KB)
  __shared__ int            s_starts[36];       // per-tile starts window

  const int tid  = threadIdx.x;
  const int lane = tid & 63;
  const int wave = tid >> 6;          // 4 waves; wave owns f-strip [wave*32, +32)
  const int quad = lane >> 4;
  const int l15  = lane & 15;

  // Persistent B fragments (W_up / W_gate) in registers, loaded once per block.
  // B-frag layout: lane holds B[k = s*32 + quad*8 + j][n = lane&15].
  bf16x8 Bu[2][4], Bg[2][4];
  float bup[2], bgt[2];
#pragma unroll
  for (int t = 0; t < 2; ++t) {
    const int f = wave * 32 + t * 16 + l15;
    bup[t] = bu[f];
    bgt[t] = bg[f];
#pragma unroll
    for (int s = 0; s < 4; ++s) {
      const int k0 = s * 32 + quad * 8;
      union { unsigned short us[8]; bf16x8 v; } a, b;
#pragma unroll
      for (int j = 0; j < 8; ++j) {
        a.us[j] = f2bf(Wu[(k0 + j) * 128 + f]);
        b.us[j] = f2bf(Wg[(k0 + j) * 128 + f]);
      }
      Bu[t][s] = a.v;
      Bg[t][s] = b.v;
    }
  }

  f32x4 ld[8];
  int tile = blockIdx.x;

  // preload first tile (64 nodes x 128 k as float4: flat = tid + i*256)
  {
    const int n0 = tile * 64;
#pragma unroll
    for (int i = 0; i < 8; ++i) {
      const int flat = tid + i * 256;
      const int n = n0 + (flat >> 5);
      const int k = (flat & 31) << 2;
      if (n < V) ld[i] = *(const f32x4*)(X + (size_t)n * 128 + k);
      else       ld[i] = f32x4{0.f, 0.f, 0.f, 0.f};
    }
  }

  for (; tile < ntiles; tile += gridDim.x) {
    const int n0    = tile * 64;
    const int n_end = min(n0 + 64, V);

    // issue early: first-graph index for this tile (latency hidden by compute)
    const int g0v = tile_seg[tile];

    // staged regs -> LDS as packed bf16 (8B ds_write)
#pragma unroll
    for (int i = 0; i < 8; ++i) {
      const int flat = tid + i * 256;
      const int n = flat >> 5;
      const int k = (flat & 31) << 2;
      const unsigned int p0 =
          (unsigned int)f2bf(ld[i][0]) | ((unsigned int)f2bf(ld[i][1]) << 16);
      const unsigned int p1 =
          (unsigned int)f2bf(ld[i][2]) | ((unsigned int)f2bf(ld[i][3]) << 16);
      *(uint2*)&Xs[n * XS_STRIDE + k] = make_uint2(p0, p1);
    }

    // issue next tile's global loads NOW; they stay in flight through the
    // lgkm-only barriers and the MFMA/reduce phases (consumed next iteration)
    const int next = tile + gridDim.x;
    if (next < ntiles) {
      const int m0 = next * 64;
#pragma unroll
      for (int i = 0; i < 8; ++i) {
        const int flat = tid + i * 256;
        const int n = m0 + (flat >> 5);
        const int k = (flat & 31) << 2;
        if (n < V) ld[i] = *(const f32x4*)(X + (size_t)n * 128 + k);
        else       ld[i] = f32x4{0.f, 0.f, 0.f, 0.f};
      }
    }

    bar_lds();   // bar1: Xs writes visible; prefetch stays in flight

    // ---- MFMA phase: 4 node sub-tiles of 16; per wave 2 f-tiles x 2 mats ----
#pragma unroll
    for (int sub = 0; sub < 4; ++sub) {
      bf16x8 A[4];
      const int nl = sub * 16 + l15;   // A-frag: A[m=lane&15][k=quad*8+j]
#pragma unroll
      for (int s = 0; s < 4; ++s)
        A[s] = *(const bf16x8*)&Xs[nl * XS_STRIDE + s * 32 + quad * 8];
#pragma unroll
      for (int t = 0; t < 2; ++t) {
        f32x4 au = {0.f, 0.f, 0.f, 0.f};
        f32x4 ag = {0.f, 0.f, 0.f, 0.f};
#pragma unroll
        for (int s = 0; s < 4; ++s) {
          au = __builtin_amdgcn_mfma_f32_16x16x32_bf16(A[s], Bu[t][s], au, 0, 0, 0);
          ag = __builtin_amdgcn_mfma_f32_16x16x32_bf16(A[s], Bg[t][s], ag, 0, 0, 0);
        }
        // D layout: col=lane&15 (feature), row=quad*4+r (node)
        const int f = wave * 32 + t * 16 + l15;
#pragma unroll
        for (int r = 0; r < 4; ++r) {
          const float up = au[r] + bup[t];
          const float gt = ag[r] + bgt[t];
          const float gv = up * __builtin_amdgcn_rcpf(1.f + __expf(-gt));
          Gs[(sub * 16 + quad * 4 + r) * GS_STRIDE + f] = gv;
        }
      }
    }

    // stage the starts window for this tile into LDS (coalesced, 1-2 lines);
    // written between bar1 and bar2 -> read-after-bar2 is race-free, and next
    // iteration's rewrite is fenced by next bar1.
    if (tid < 36) s_starts[tid] = starts[min(g0v + tid, G)];

    bar_lds();   // bar2: Gs + s_starts visible

    // ---- segment reduction: per-graph row sums -> one atomic per (g,f) ----
    {
      const int fcol = tid & 127;
      const int half = tid >> 7;       // halves take alternating graphs
      int i = 0;
      int sg = s_starts[0];
      while (sg < n_end && i < 35) {
        const int snext = s_starts[i + 1];
        if (((g0v + i) & 1) == half) {
          const int r0 = max(sg, n0) - n0;
          const int r1 = min(snext - 1, n_end) - n0;  // excludes graph's last node
          if (r1 > r0) {
            float a0 = 0.f, a1 = 0.f, a2 = 0.f, a3 = 0.f;
            int r = r0;
            for (; r + 4 <= r1; r += 4) {
              a0 += Gs[(r + 0) * GS_STRIDE + fcol];
              a1 += Gs[(r + 1) * GS_STRIDE + fcol];
              a2 += Gs[(r + 2) * GS_STRIDE + fcol];
              a3 += Gs[(r + 3) * GS_STRIDE + fcol];
            }
            for (; r < r1; ++r) a0 += Gs[r * GS_STRIDE + fcol];
            const float acc = (a0 + a1) + (a2 + a3);
            atomicAdd(&gsum[(size_t)(g0v + i) * 128 + fcol], acc);
          }
        }
        sg = snext;
        ++i;
      }
    }
    // no end-of-loop barrier: next iteration's bar1 fences Xs/Gs/s_starts reuse
  }
}

__global__ __launch_bounds__(256)
void stage2_kernel(const float* __restrict__ Wf, const float* __restrict__ bfv,
                   float* __restrict__ out, int G)
{
  __shared__ float Gsm[32 * 132];
  const int g0  = blockIdx.x * 32;
  const int tid = threadIdx.x;

  // stage this block's 32 graph_sums rows (then safe to overwrite in-place)
  for (int i = tid; i < 32 * 32; i += 256) {
    const int r = i >> 5;
    const int c = (i & 31) << 2;
    const int g = g0 + r;
    f32x4 v = {0.f, 0.f, 0.f, 0.f};
    if (g < G) v = *(const f32x4*)(out + (size_t)g * 128 + c);
    *(f32x4*)&Gsm[r * 132 + c] = v;
  }
  __syncthreads();

  const int fq  = tid & 31;
  const int f0  = fq << 2;            // 4 consecutive features
  const int grp = tid >> 5;           // 8 groups x 4 graphs
  float acc[4][4];
#pragma unroll
  for (int i = 0; i < 4; ++i)
#pragma unroll
    for (int j = 0; j < 4; ++j) acc[i][j] = 0.f;

#pragma unroll 4
  for (int k = 0; k < 128; ++k) {
    const f32x4 w = *(const f32x4*)(Wf + (size_t)k * 128 + f0);
#pragma unroll
    for (int i = 0; i < 4; ++i) {
      const float gv = Gsm[(grp * 4 + i) * 132 + k];
      acc[i][0] += gv * w[0];
      acc[i][1] += gv * w[1];
      acc[i][2] += gv * w[2];
      acc[i][3] += gv * w[3];
    }
  }

  const f32x4 bb = *(const f32x4*)(bfv + f0);
#pragma unroll
  for (int i = 0; i < 4; ++i) {
    const int g = g0 + grp * 4 + i;
    if (g < G) {
      f32x4 o = {acc[i][0] + bb[0], acc[i][1] + bb[1],
                 acc[i][2] + bb[2], acc[i][3] + bb[3]};
      *(f32x4*)(out + (size_t)g * 128 + f0) = o;
    }
  }
}

extern "C" void kernel_launch(void* const* d_in, const int* in_sizes, int n_in,
                              void* d_out, int out_size, void* d_ws, size_t ws_size,
                              hipStream_t stream)
{
  const float* X      = (const float*)d_in[0];
  const float* Wu     = (const float*)d_in[1];
  const float* bu     = (const float*)d_in[2];
  const float* Wg     = (const float*)d_in[3];
  const float* bg     = (const float*)d_in[4];
  const float* Wf     = (const float*)d_in[5];
  const float* bf_    = (const float*)d_in[6];
  const int*   starts = (const int*)d_in[7];

  const int G = in_sizes[7] - 1;
  const int V = in_sizes[0] / 128;
  const int ntiles = (V + 63) / 64;

  int*   tile_seg = (int*)d_ws;          // ntiles ints (~31 KB)
  float* gsum     = (float*)d_out;       // graph_sums accumulates in d_out

  hipMemsetAsync(d_out, 0, (size_t)G * 128 * sizeof(float), stream);
  tile_seg_kernel<<<(ntiles + 255) / 256, 256, 0, stream>>>(starts, tile_seg, ntiles, G);
  stage1_kernel<<<512, 256, 0, stream>>>(X, Wu, bu, Wg, bg, starts, tile_seg,
                                         gsum, V, G, ntiles);
  stage2_kernel<<<(G + 31) / 32, 256, 0, stream>>>(Wf, bf_, gsum, G);
}